// Round 11
// baseline (297.798 us; speedup 1.0000x reference)
//
#include <hip/hip_runtime.h>
#include <hip/hip_bf16.h>

// AAE_GCN round 11: GEMM fragment loads vectorized.
//  r10: gemm 68.5us, MfmaUtil 5.8%, 0 bank conf -> diagnosis: 64 scalar
//  ds_read_u16/iter with serialized ~60-120cy latency (4Kcy/iter).
//  Fix: LDS [m][k] transposed (RS=72B): frag read = 2x ds_read_b64 (16 vec
//  reads/iter). Staging loads 2 adjacent k-rows, packs u32 pairs, 8x b32
//  writes. Plus register-prefetch pipeline to hide HBM latency under MFMA.

#define LRELU(v) ((v) > 0.f ? (v) : 0.01f * (v))

static constexpr int Bb = 512;
static constexpr int Nn = 20000;
static constexpr int Ee = 640000;
static constexpr int KPAD = 20480;
static constexpr int RSU = 36;  // LDS row stride (ushorts) = 72B
static constexpr int RSW = 18;  // in u32

typedef __attribute__((ext_vector_type(8))) short short8;
typedef __attribute__((ext_vector_type(4))) short short4v;
typedef __attribute__((ext_vector_type(4))) float f32x4;

__device__ __forceinline__ ushort f2bf(float f) {
  uint u = __builtin_bit_cast(uint, f);
  u = u + 0x7FFFu + ((u >> 16) & 1u);  // RTNE
  return (ushort)(u >> 16);
}
__device__ __forceinline__ float bfLo(uint u) {
  return __builtin_bit_cast(float, u << 16);
}
__device__ __forceinline__ float bfHi(uint u) {
  return __builtin_bit_cast(float, u & 0xffff0000u);
}

// ---------- transpose + noise + dinv-fold -> xs chunks [NC][Nn][128] bf16 ----------
__global__ void transpose_xs_k(const float* __restrict__ a, const float* __restrict__ nz,
                               const float* __restrict__ dinv, ushort* __restrict__ xs, int b0) {
  __shared__ ushort tile[64][65];
  int c0 = blockIdx.x * 64;
  int p = blockIdx.y;
  int chunk = p >> 1;
  int sub = (p & 1) * 64;
  int rbase = b0 + p * 64;
  for (int i = threadIdx.x; i < 64 * 64; i += 256) {
    int rr = i >> 6, cc = i & 63;
    int r = rbase + rr, c = c0 + cc;
    ushort v = 0;
    if (c < Nn) {
      size_t idx = (size_t)r * Nn + c;
      v = f2bf(dinv[c] * (a[idx] + 0.1f * nz[idx]));
    }
    tile[rr][cc] = v;
  }
  __syncthreads();
  for (int i = threadIdx.x; i < 64 * 64; i += 256) {
    int cc = i >> 6, rr = i & 63;
    int c = c0 + cc;
    if (c < Nn) xs[(size_t)chunk * Nn * 128 + (size_t)c * 128 + sub + rr] = tile[rr][cc];
  }
}

// ---------- degree histogram + range check ----------
__global__ void hist_check_k(const int* __restrict__ src, const int* __restrict__ dst, int E,
                             int* __restrict__ cnt, int* __restrict__ flag) {
  int i = blockIdx.x * 256 + threadIdx.x;
  if (i < E) {
    int s = src[i], d = dst[i];
    if ((unsigned)s >= (unsigned)Nn || (unsigned)d >= (unsigned)Nn) {
      atomicExch(flag, 1);
    } else {
      atomicAdd(&cnt[d], 1);
    }
  }
}

// ---------- offsets via wave prefix + atomic bump ----------
__global__ void offs_k(const int* __restrict__ cnt, int* __restrict__ offs,
                       int* __restrict__ cursor, float* __restrict__ dinv,
                       int* __restrict__ bump) {
  int i = blockIdx.x * 256 + threadIdx.x;
  int l = threadIdx.x & 63;
  int v = (i < Nn) ? cnt[i] : 0;
  int x = v;
#pragma unroll
  for (int d = 1; d < 64; d <<= 1) {
    int t = __shfl_up(x, d);
    if (l >= d) x += t;
  }
  int total = __shfl(x, 63);
  int base = 0;
  if (l == 0) base = atomicAdd(bump, total);
  base = __shfl(base, 0);
  int excl = base + x - v;
  if (i < Nn) {
    offs[i] = excl;
    cursor[i] = excl;
    dinv[i] = rsqrtf(2.0f + (float)v);
  }
}

// ---------- scatter edges (pre-scaled byte offsets) ----------
__global__ void scatter_k(const int* __restrict__ src, const int* __restrict__ dst, int E,
                          int* __restrict__ cursor, uint* __restrict__ eOff) {
  int i = blockIdx.x * 256 + threadIdx.x;
  if (i < E) {
    int s = src[i], d = dst[i];
    if ((unsigned)s >= (unsigned)Nn || (unsigned)d >= (unsigned)Nn) return;
    int p = atomicAdd(&cursor[d], 1);
    eOff[p] = (uint)s * 256u;
  }
}

// ---------- chunk SpMM (verified r9) ----------
__global__ __launch_bounds__(256) void spmm_chunk_k(
    const ushort* __restrict__ xs, const uint* __restrict__ eOff, const int* __restrict__ offs,
    const int* __restrict__ cnt, const float* __restrict__ dinv, const float* __restrict__ wg,
    const float* __restrict__ bg, ushort* __restrict__ gcnT, int NC) {
  __shared__ uint sIdx[4][64];
  int bid = blockIdx.x;
  int chunk = bid % NC;
  int ngrp = bid / NC;
  int wv = threadIdx.x >> 6, l = threadIdx.x & 63;
  int n = ngrp * 4 + wv;
  int o = offs[n], c = cnt[n];
  const char* base = (const char*)(xs + (size_t)chunk * Nn * 128) + l * 4;
  const uint* ep = eOff + o;
  uint su = *(const uint*)(base + (size_t)n * 256);
  float a00 = 2.0f * bfLo(su), a01 = 2.0f * bfHi(su);
  float a10 = 0.f, a11 = 0.f;

  for (int bi = 0; bi < c; bi += 64) {
    int rem = c - bi;
    if (rem > 64) rem = 64;
    sIdx[wv][l] = (l < rem) ? ep[bi + l] : 0u;
    int i = 0;
    for (; i + 8 <= rem; i += 8) {
      uint u[8];
#pragma unroll
      for (int j = 0; j < 8; ++j) u[j] = *(const uint*)(base + sIdx[wv][i + j]);
#pragma unroll
      for (int j = 0; j < 8; j += 2) {
        a00 += bfLo(u[j]);
        a01 += bfHi(u[j]);
        a10 += bfLo(u[j + 1]);
        a11 += bfHi(u[j + 1]);
      }
    }
    for (; i < rem; ++i) {
      uint u = *(const uint*)(base + sIdx[wv][i]);
      a00 += bfLo(u);
      a01 += bfHi(u);
    }
  }

  float wdn = wg[0] * dinv[n], bb = bg[0];
  float v0 = wdn * (a00 + a10) + bb;
  float v1 = wdn * (a01 + a11) + bb;
  v0 = LRELU(v0);
  v1 = LRELU(v1);
  uint pk = (uint)f2bf(v0) | ((uint)f2bf(v1) << 16);
  *(uint*)&gcnT[(size_t)chunk * KPAD * 128 + (size_t)n * 128 + 2 * l] = pk;
}

// ---------- MFMA GEMM v3: 128x128 tile, BK=32, [m][k] LDS, vector frag reads,
// ---------- register-prefetch pipeline ----------
template <bool SPLITK>
__global__ __launch_bounds__(256) void mfma_gemm3(const ushort* __restrict__ AT, int lda, int pw,
                                                  size_t pstride, const float* __restrict__ B,
                                                  int ldb, int KB, int Nv, int iters,
                                                  float* __restrict__ C, int ldc,
                                                  const float* __restrict__ bias) {
  __shared__ ushort As[128 * RSU];
  __shared__ ushort Bs[128 * RSU];
  int n0 = blockIdx.x * 128, m0 = blockIdx.y * 128;
  int k0 = blockIdx.z * iters * 32;
  int tid = threadIdx.x;
  int kp = tid >> 4;       // k-pair index 0..15 (rows 2kp, 2kp+1)
  int c8 = (tid & 15) * 8; // 8-wide m/n group
  int l = tid & 63, w = tid >> 6;
  int wr = w >> 1, wc = w & 1;
  int lrow = l & 15, lkg = l >> 4;
  const ushort* Ap = AT + (size_t)(m0 / pw) * pstride + (m0 % pw);
  int bcol = n0 + c8;
  bool bok = bcol < Nv;
  f32x4 acc[4][4] = {};

  // prefetch registers (named, static — no runtime indexing)
  uint4 pa0, pa1;
  float4 pb00, pb01, pb10, pb11;

#define GLOAD(KG)                                                                       \
  {                                                                                     \
    int kq = (KG) + 2 * kp;                                                             \
    pa0 = *(const uint4*)&Ap[(size_t)kq * lda + c8];                                    \
    pa1 = *(const uint4*)&Ap[(size_t)(kq + 1) * lda + c8];                              \
    pb00 = pb01 = pb10 = pb11 = float4{0.f, 0.f, 0.f, 0.f};                             \
    if (bok) {                                                                          \
      if (kq < KB) {                                                                    \
        const float4* bp = (const float4*)(B + (size_t)kq * ldb + bcol);                \
        pb00 = bp[0];                                                                   \
        pb01 = bp[1];                                                                   \
      }                                                                                 \
      if (kq + 1 < KB) {                                                                \
        const float4* bp = (const float4*)(B + (size_t)(kq + 1) * ldb + bcol);          \
        pb10 = bp[0];                                                                   \
        pb11 = bp[1];                                                                   \
      }                                                                                 \
    }                                                                                   \
  }

  GLOAD(k0);

  for (int kt = 0; kt < iters; ++kt) {
    // pack reg pairs -> u32 (k, k+1) per column
    uint wa[8], wb[8];
    wa[0] = (pa0.x & 0xffffu) | (pa1.x << 16);
    wa[1] = (pa0.x >> 16) | (pa1.x & 0xffff0000u);
    wa[2] = (pa0.y & 0xffffu) | (pa1.y << 16);
    wa[3] = (pa0.y >> 16) | (pa1.y & 0xffff0000u);
    wa[4] = (pa0.z & 0xffffu) | (pa1.z << 16);
    wa[5] = (pa0.z >> 16) | (pa1.z & 0xffff0000u);
    wa[6] = (pa0.w & 0xffffu) | (pa1.w << 16);
    wa[7] = (pa0.w >> 16) | (pa1.w & 0xffff0000u);
    wb[0] = (uint)f2bf(pb00.x) | ((uint)f2bf(pb10.x) << 16);
    wb[1] = (uint)f2bf(pb00.y) | ((uint)f2bf(pb10.y) << 16);
    wb[2] = (uint)f2bf(pb00.z) | ((uint)f2bf(pb10.z) << 16);
    wb[3] = (uint)f2bf(pb00.w) | ((uint)f2bf(pb10.w) << 16);
    wb[4] = (uint)f2bf(pb01.x) | ((uint)f2bf(pb11.x) << 16);
    wb[5] = (uint)f2bf(pb01.y) | ((uint)f2bf(pb11.y) << 16);
    wb[6] = (uint)f2bf(pb01.z) | ((uint)f2bf(pb11.z) << 16);
    wb[7] = (uint)f2bf(pb01.w) | ((uint)f2bf(pb11.w) << 16);
    __syncthreads();
    {
      uint* aw = (uint*)As;
      uint* bw = (uint*)Bs;
#pragma unroll
      for (int j = 0; j < 8; ++j) {
        aw[(c8 + j) * RSW + kp] = wa[j];
        bw[(c8 + j) * RSW + kp] = wb[j];
      }
    }
    __syncthreads();
    // issue next-iter global loads now; latency hides under frag reads + MFMAs
    if (kt + 1 < iters) GLOAD(k0 + (kt + 1) * 32);
    // fragments: row m, k = lkg*8..+8 -> two b64 reads
    short8 a[4], b[4];
#pragma unroll
    for (int mi = 0; mi < 4; ++mi) {
      int m = wr * 64 + mi * 16 + lrow;
      const short4v* p = (const short4v*)&As[m * RSU + lkg * 8];
      a[mi] = __builtin_shufflevector(p[0], p[1], 0, 1, 2, 3, 4, 5, 6, 7);
    }
#pragma unroll
    for (int nj = 0; nj < 4; ++nj) {
      int n = wc * 64 + nj * 16 + lrow;
      const short4v* p = (const short4v*)&Bs[n * RSU + lkg * 8];
      b[nj] = __builtin_shufflevector(p[0], p[1], 0, 1, 2, 3, 4, 5, 6, 7);
    }
#pragma unroll
    for (int mi = 0; mi < 4; ++mi)
#pragma unroll
      for (int nj = 0; nj < 4; ++nj)
        acc[mi][nj] = __builtin_amdgcn_mfma_f32_16x16x32_bf16(a[mi], b[nj], acc[mi][nj], 0, 0, 0);
  }
#undef GLOAD

  // epilogue: D col = lane&15, row = (lane>>4)*4 + r
#pragma unroll
  for (int mi = 0; mi < 4; ++mi)
#pragma unroll
    for (int nj = 0; nj < 4; ++nj)
#pragma unroll
      for (int r = 0; r < 4; ++r) {
        int row = m0 + wr * 64 + mi * 16 + lkg * 4 + r;
        int col = n0 + wc * 64 + nj * 16 + lrow;
        if (SPLITK) {
          atomicAdd(&C[(size_t)row * ldc + col], acc[mi][nj][r]);
        } else if (col < Nv) {
          float v = acc[mi][nj][r] + bias[col];
          C[(size_t)row * ldc + col] = LRELU(v);
        }
      }
}

// ---------- tail v3 (verified r9) ----------
__global__ __launch_bounds__(256) void tail2_k(
    const float* __restrict__ h1, const float* __restrict__ c1, const float* __restrict__ W2,
    const float* __restrict__ c2, const float* __restrict__ W3, const float* __restrict__ c3,
    const float* __restrict__ Wd1, const float* __restrict__ cd1, const float* __restrict__ Wd2,
    const float* __restrict__ cd2, const float* __restrict__ Wg1, const float* __restrict__ cg1,
    const float* __restrict__ Wg2, const float* __restrict__ cg2, const float* __restrict__ Wg3,
    const float* __restrict__ cg3, float* __restrict__ out_z, float* __restrict__ out_d,
    ushort* __restrict__ d2bfT, int BT, int b0) {
  __shared__ float s_h1[512];
  __shared__ float s_h2[256];
  __shared__ float s_z[64];
  __shared__ float s_d1[256];
  __shared__ float s_g1[256];
  __shared__ float s_g2[256];
  __shared__ float s_part[4][256];
  __shared__ float s_red[4];
  int rl = blockIdx.x;
  int rg = b0 + rl;
  int t = threadIdx.x;
  int w = t >> 6, l = t & 63;

  {
    float r0 = h1[(size_t)rl * 512 + t] + c1[t];
    float r1 = h1[(size_t)rl * 512 + t + 256] + c1[t + 256];
    s_h1[t] = LRELU(r0);
    s_h1[t + 256] = LRELU(r1);
  }
  __syncthreads();

  {
    int c4 = l * 4;
    float a0 = 0.f, a1 = 0.f, a2 = 0.f, a3 = 0.f;
#pragma unroll 8
    for (int k = w * 128; k < w * 128 + 128; ++k) {
      float4 wv = *(const float4*)&W2[(size_t)k * 256 + c4];
      float x = s_h1[k];
      a0 += x * wv.x; a1 += x * wv.y; a2 += x * wv.z; a3 += x * wv.w;
    }
    float4 pv = {a0, a1, a2, a3};
    *(float4*)&s_part[w][c4] = pv;
  }
  __syncthreads();
  s_h2[t] = LRELU(s_part[0][t] + s_part[1][t] + s_part[2][t] + s_part[3][t] + c2[t]);
  __syncthreads();

  {
    int c = t >> 2, p = t & 3;
    float a = 0.f;
#pragma unroll 8
    for (int k = p * 64; k < p * 64 + 64; ++k) a += s_h2[k] * W3[(size_t)k * 64 + c];
    s_part[p][c] = a;
  }
  __syncthreads();
  if (t < 64) {
    float v = s_part[0][t] + s_part[1][t] + s_part[2][t] + s_part[3][t] + c3[t];
    v = LRELU(v);
    s_z[t] = v;
    out_z[(size_t)rg * 64 + t] = v;
  }
  __syncthreads();

  {
    float a = 0.f;
#pragma unroll
    for (int k = 0; k < 64; ++k) a += s_z[k] * Wd1[(size_t)k * 256 + t];
    s_d1[t] = LRELU(a + cd1[t]);
  }
  {
    float a = 0.f;
#pragma unroll
    for (int k = 0; k < 64; ++k) a += s_z[k] * Wg1[(size_t)k * 256 + t];
    s_g1[t] = LRELU(a + cg1[t]);
  }
  __syncthreads();

  {
    int g = t & 127, p = t >> 7;
    int c4 = g * 4;
    float a0 = 0.f, a1 = 0.f, a2 = 0.f, a3 = 0.f;
#pragma unroll 8
    for (int k = p * 128; k < p * 128 + 128; ++k) {
      float4 wv = *(const float4*)&Wd2[(size_t)k * 512 + c4];
      float x = s_d1[k];
      a0 += x * wv.x; a1 += x * wv.y; a2 += x * wv.z; a3 += x * wv.w;
    }
    float* sp = &s_part[0][0];
    float4 pv = {a0, a1, a2, a3};
    *(float4*)&sp[p * 512 + c4] = pv;
  }
  __syncthreads();
  {
    const float* sp = &s_part[0][0];
#pragma unroll
    for (int cc = 0; cc < 2; ++cc) {
      int c = t + cc * 256;
      float v = sp[c] + sp[512 + c] + cd2[c];
      v = LRELU(v);
      d2bfT[(size_t)c * BT + rl] = f2bf(v);
    }
  }
  __syncthreads();

  {
    int c4 = l * 4;
    float a0 = 0.f, a1 = 0.f, a2 = 0.f, a3 = 0.f;
#pragma unroll 8
    for (int k = w * 64; k < w * 64 + 64; ++k) {
      float4 wv = *(const float4*)&Wg2[(size_t)k * 256 + c4];
      float x = s_g1[k];
      a0 += x * wv.x; a1 += x * wv.y; a2 += x * wv.z; a3 += x * wv.w;
    }
    float4 pv = {a0, a1, a2, a3};
    *(float4*)&s_part[w][c4] = pv;
  }
  __syncthreads();
  s_g2[t] = LRELU(s_part[0][t] + s_part[1][t] + s_part[2][t] + s_part[3][t] + cg2[t]);
  __syncthreads();

  {
    float p = s_g2[t] * Wg3[t];
#pragma unroll
    for (int o = 32; o > 0; o >>= 1) p += __shfl_down(p, o);
    if ((t & 63) == 0) s_red[t >> 6] = p;
    __syncthreads();
    if (t == 0) {
      float s = s_red[0] + s_red[1] + s_red[2] + s_red[3] + cg3[0];
      out_d[rg] = 1.f / (1.f + __expf(-s));
    }
  }
}

// ---------- sentinels ----------
__global__ void sentinel_k(float* out, float val) { out[0] = val; }
__global__ void flag_sentinel_k(float* out, const int* flag) {
  if (*flag != 0) out[0] = 70000.0f;
}

extern "C" void kernel_launch(void* const* d_in, const int* in_sizes, int n_in,
                              void* d_out, int out_size, void* d_ws, size_t ws_size,
                              hipStream_t stream) {
  const float* data = (const float*)d_in[0];
  const float* noise = (const float*)d_in[1];
  const int* edge = (const int*)d_in[2];
  const int* esrc_in = edge;
  const int* edst_in = edge + Ee;
  const float* w_gcn = (const float*)d_in[3];
  const float* b_gcn = (const float*)d_in[4];
  const float* enc1_w = (const float*)d_in[5];
  const float* enc1_b = (const float*)d_in[6];
  const float* enc2_w = (const float*)d_in[7];
  const float* enc2_b = (const float*)d_in[8];
  const float* enc3_w = (const float*)d_in[9];
  const float* enc3_b = (const float*)d_in[10];
  const float* dec1_w = (const float*)d_in[11];
  const float* dec1_b = (const float*)d_in[12];
  const float* dec2_w = (const float*)d_in[13];
  const float* dec2_b = (const float*)d_in[14];
  const float* dec3_w = (const float*)d_in[15];
  const float* dec3_b = (const float*)d_in[16];
  const float* disc1_w = (const float*)d_in[17];
  const float* disc1_b = (const float*)d_in[18];
  const float* disc2_w = (const float*)d_in[19];
  const float* disc2_b = (const float*)d_in[20];
  const float* disc3_w = (const float*)d_in[21];
  const float* disc3_b = (const float*)d_in[22];

  int BT = 128;
  if (ws_size >= 48500000u) BT = 512;
  else if (ws_size >= 24392500u) BT = 256;
  int NC = BT / 128;
  if (NC < 1) NC = 1;

  char* w = (char*)d_ws;
  size_t o = 0;
  auto alloc = [&](size_t bytes) {
    size_t r = o;
    o = (o + bytes + 15) & ~(size_t)15;
    return r;
  };
  ushort* xs = (ushort*)(w + alloc((size_t)Nn * BT * 2));
  ushort* gcnT = (ushort*)(w + alloc((size_t)KPAD * BT * 2));
  float* h1 = (float*)(w + alloc((size_t)BT * 512 * 4));
  ushort* d2bfT = (ushort*)(w + alloc((size_t)512 * BT * 2));
  float* dinv = (float*)(w + alloc(Nn * 4));
  int* cnt = (int*)(w + alloc(Nn * 4));
  int* offs = (int*)(w + alloc(Nn * 4));
  int* cursor = (int*)(w + alloc(Nn * 4));
  uint* eOff = (uint*)(w + alloc(Ee * 4));
  int* flag = (int*)(w + alloc(16));

  float* outp = (float*)d_out;
  float* out_dec = outp;
  float* out_z = outp + (size_t)Bb * Nn;
  float* out_d = out_z + (size_t)Bb * 64;

  static const int expect_sizes[23] = {
      10240000, 10240000, 1280000, 1, 1,
      10240000, 512, 131072, 256, 16384, 64,
      16384, 256, 131072, 512, 10240000, 20000,
      16384, 256, 65536, 256, 256, 1};
  float host_sentinel = 0.f;
  if (n_in != 23) host_sentinel = 50000.f;
  else if (out_size != 10273280) host_sentinel = 80000.f;
  else {
    for (int i = 0; i < 23; ++i)
      if (in_sizes[i] != expect_sizes[i]) { host_sentinel = 100000.f + 1000.f * i; break; }
  }

  // ---- CSR build (once) ----
  hipMemsetAsync(cnt, 0, Nn * sizeof(int), stream);
  hipMemsetAsync(flag, 0, 2 * sizeof(int), stream);
  hist_check_k<<<(Ee + 255) / 256, 256, 0, stream>>>(esrc_in, edst_in, Ee, cnt, flag);
  offs_k<<<(Nn + 255) / 256, 256, 0, stream>>>(cnt, offs, cursor, dinv, flag + 1);
  scatter_k<<<(Ee + 255) / 256, 256, 0, stream>>>(esrc_in, edst_in, Ee, cursor, eOff);
  hipMemsetAsync(gcnT, 0, (size_t)KPAD * BT * 2, stream);

  // ---- per batch-tile pipeline ----
  for (int b0 = 0; b0 < Bb; b0 += BT) {
    {
      dim3 g((Nn + 63) / 64, BT / 64);
      transpose_xs_k<<<g, 256, 0, stream>>>(data, noise, dinv, xs, b0);
    }
    spmm_chunk_k<<<(Nn / 4) * NC, 256, 0, stream>>>(xs, eOff, offs, cnt, dinv, w_gcn, b_gcn,
                                                    gcnT, NC);
    hipMemsetAsync(h1, 0, (size_t)BT * 512 * 4, stream);
    {
      // enc1: M=BT N=512 K=20000(pad 20480), splitK 32 x (20 x 32)
      dim3 g(512 / 128, BT / 128, 32);
      mfma_gemm3<true><<<g, 256, 0, stream>>>(gcnT, 128, 128, (size_t)KPAD * 128, enc1_w, 512,
                                              Nn, 512, 20, h1, 512, nullptr);
    }
    tail2_k<<<BT, 256, 0, stream>>>(h1, enc1_b, enc2_w, enc2_b, enc3_w, enc3_b, dec1_w, dec1_b,
                                    dec2_w, dec2_b, disc1_w, disc1_b, disc2_w, disc2_b, disc3_w,
                                    disc3_b, out_z, out_d, d2bfT, BT, b0);
    {
      // dec3: M=BT N=20000 K=512 (16 x 32)
      dim3 g((Nn + 127) / 128, BT / 128, 1);
      mfma_gemm3<false><<<g, 256, 0, stream>>>(d2bfT, BT, BT, 0, dec3_w, Nn, 512, Nn, 16,
                                               out_dec + (size_t)b0 * Nn, Nn, dec3_b);
    }
  }

  flag_sentinel_k<<<1, 1, 0, stream>>>(out_dec, flag);
  if (host_sentinel != 0.f) sentinel_k<<<1, 1, 0, stream>>>(out_dec, host_sentinel);
}